// Round 9
// baseline (449.560 us; speedup 1.0000x reference)
//
#include <hip/hip_runtime.h>
#include <hip/hip_bf16.h>

namespace {
constexpr int kN    = 8192;
constexpr int kFin  = 512;
constexpr int kFout = 64;
constexpr float kAlpha = 0.2f;
constexpr int kJSplit = 4;                  // j-range split for k_attn
constexpr int kJLen   = kN / kJSplit;       // 2048
constexpr int kChunks = kJLen / 128;        // 16

using bf16x8 = __attribute__((ext_vector_type(8))) short;
using f32x4  = __attribute__((ext_vector_type(4))) float;

__device__ __forceinline__ unsigned short f2bf(float x) {
  return __builtin_bit_cast(unsigned short, __float2bfloat16(x));
}
__device__ __forceinline__ float lrelu(float x) {
  return fmaxf(x, kAlpha * x);   // valid since 0<alpha<1
}
// monotone float<->uint order-preserving map (for atomicMax on float)
__device__ __forceinline__ unsigned int fkey(float x) {
  unsigned int b = __float_as_uint(x);
  return (b & 0x80000000u) ? ~b : (b | 0x80000000u);
}
__device__ __forceinline__ float fdec(unsigned int k) {
  return (k & 0x80000000u) ? __uint_as_float(k ^ 0x80000000u) : __uint_as_float(~k);
}
} // namespace

// ---------------------------------------------------------------------------
// k_prep: (a) adj->bitmask sweep on blocks 0..2047 (FIRST, so the 268-MB
// stream starts with full machine and coherent fronts); (b) linear part on
// blocks 2048..2559 (tail-fills). Sweep: per iteration the mask-grid reads
// one contiguous 8-MB window (wave = 64 consecutive int4); unroll 4 -> 4
// outstanding loads/wave against ~900-cyc HBM latency.
// ---------------------------------------------------------------------------
__global__ __launch_bounds__(256) void k_prep(
    const int* __restrict__ adj, const float* __restrict__ X,
    const float* __restrict__ W, const float* __restrict__ A,
    unsigned long long* __restrict__ mask, unsigned short* __restrict__ hTf,
    float* __restrict__ s_src, float* __restrict__ s_dst,
    unsigned int* __restrict__ Smax_u)
{
  const int t = threadIdx.x;
  const int wv = t >> 6, lane = t & 63;

  if (blockIdx.x < 2048) {
    // ---------------- bitmask sweep ----------------
    const int mwave = blockIdx.x * 4 + wv;               // 0..8191
    const int4* __restrict__ a4 = (const int4*)adj;
    const int grp = lane >> 4;                           // word within wave span
    const unsigned long long shft = 4ull * (lane & 15);
#pragma unroll 4
    for (int it = 0; it < 32; ++it) {
      const size_t base4 = ((size_t)it * 8192 + mwave) * 64;   // int4 idx
      const int4 v = a4[base4 + lane];                   // 1 KB/wave, coalesced
      const unsigned int nib = (v.x > 0 ? 1u : 0u) | (v.y > 0 ? 2u : 0u) |
                               (v.z > 0 ? 4u : 0u) | (v.w > 0 ? 8u : 0u);
      unsigned long long val = (unsigned long long)nib << shft;
      val |= __shfl_xor(val, 1, 64);
      val |= __shfl_xor(val, 2, 64);
      val |= __shfl_xor(val, 4, 64);
      val |= __shfl_xor(val, 8, 64);                     // 16-lane group OR
      if ((lane & 15) == 0) {
        const size_t baseInt = base4 * 4;
        const size_t row = baseInt >> 13;                // / 8192
        const size_t jw  = (baseInt & 8191) >> 6;
        mask[row * 128 + jw + grp] = val;
      }
    }
    return;
  }

  // ---------------- linear part (proven r7/r8) ----------------
  const int wvu = __builtin_amdgcn_readfirstlane(wv);
  const int f = lane;
  const int i0 = (blockIdx.x - 2048) * 16;
  const int r0l = wvu * 4;

  __shared__ unsigned short h_sm[16][64];
  __shared__ float red[4];

  const float* x0 = X + (size_t)(i0 + r0l) * kFin;      // wave-uniform base
  float acc0 = 0.f, acc1 = 0.f, acc2 = 0.f, acc3 = 0.f;
#pragma unroll 2
  for (int k = 0; k < kFin; k += 4) {
    const float4 xa = *(const float4*)(x0 + k);
    const float4 xb = *(const float4*)(x0 + kFin + k);
    const float4 xc = *(const float4*)(x0 + 2 * kFin + k);
    const float4 xd = *(const float4*)(x0 + 3 * kFin + k);
#pragma unroll
    for (int j = 0; j < 4; ++j) {
      const float wk = W[(k + j) * kFout + f];
      acc0 = fmaf(((const float*)&xa)[j], wk, acc0);
      acc1 = fmaf(((const float*)&xb)[j], wk, acc1);
      acc2 = fmaf(((const float*)&xc)[j], wk, acc2);
      acc3 = fmaf(((const float*)&xd)[j], wk, acc3);
    }
  }

  const float asrc = A[f], adst = A[kFout + f];
  float accs[4] = {acc0, acc1, acc2, acc3};
  float dmax = -3.4e38f;
#pragma unroll
  for (int r = 0; r < 4; ++r) {
    float vs = accs[r] * asrc;
    float vd = accs[r] * adst;
#pragma unroll
    for (int off = 32; off > 0; off >>= 1) {
      vs += __shfl_xor(vs, off, 64);
      vd += __shfl_xor(vd, off, 64);
    }
    if (f == 0) {
      s_src[i0 + r0l + r] = vs;
      s_dst[i0 + r0l + r] = vd;
      dmax = fmaxf(dmax, vd);
    }
    h_sm[r0l + r][f] = f2bf(accs[r]);
  }
  if (f == 0) red[wvu] = dmax;
  __syncthreads();
  if (t == 0) {
    float m = fmaxf(fmaxf(red[0], red[1]), fmaxf(red[2], red[3]));
    atomicMax(Smax_u, fkey(m));
  }

  if (t < 128) {
    const int jblk = i0 >> 5, half = (i0 >> 4) & 1;
    const int w = t >> 5, li = t & 31;
    const int ln = half * 32 + li;
    const int ql = li >> 4, fcol = w * 16 + (li & 15);
    bf16x8 v;
#pragma unroll
    for (int e = 0; e < 8; ++e) v[e] = (short)h_sm[ql * 8 + e][fcol];
    *(bf16x8*)(hTf + (size_t)jblk * 2048 + w * 512 + (size_t)ln * 8) = v;
  }
}

// ---------------------------------------------------------------------------
// k_attn v9: 32-ROW blocks — each wave computes TWO 16-row A-fragments (rows
// i0..i0+15 and i0+16..i0+31) sharing ONE hv B-fragment set => hTf L2 traffic
// halves (512->256 MB) and 8 independent MFMAs per chunk hide L2 latency.
// grid 1024 (256 i-blocks x 4 j-quarters) x 256 thr. Barrier-free main loop;
// depth-2 NAMED register prefetch for mask words and s_dst (r5 scratch lesson).
// ---------------------------------------------------------------------------
__global__ __launch_bounds__(256, 4) void k_attn(
    const unsigned long long* __restrict__ mask,
    const unsigned short* __restrict__ hTf,
    const float* __restrict__ s_src, const float* __restrict__ s_dst,
    const unsigned int* __restrict__ Smax_u, float* __restrict__ accp,
    float* __restrict__ lp)
{
  const int t = threadIdx.x;
  const int wv = t >> 6, lane = t & 63;
  const int b = blockIdx.x;
  const int i0 = (b >> 2) * 32;
  const int jbase = (b & 3) * kJLen;
  const int mrow = lane & 15, quad = lane >> 4;

  __shared__ float Racc[4][32][64];   // 32 KB
  __shared__ float Rl[4][32];

  const float S = fdec(*Smax_u);
  const float ssA = s_src[i0 + mrow];
  const float ssB = s_src[i0 + 16 + mrow];
  const float mrA = lrelu(ssA + S);
  const float mrB = lrelu(ssB + S);

  float lA = 0.f, lB = 0.f;
  f32x4 aA0 = {0,0,0,0}, aA1 = {0,0,0,0}, aA2 = {0,0,0,0}, aA3 = {0,0,0,0};
  f32x4 aB0 = {0,0,0,0}, aB1 = {0,0,0,0}, aB2 = {0,0,0,0}, aB3 = {0,0,0,0};

  const unsigned long long* mptrA =
      mask + (size_t)(i0 + mrow) * 128 + (jbase >> 6) + (wv >> 1);
  const unsigned long long* mptrB = mptrA + 16 * 128;
  const int sh = (wv & 1) * 32 + quad * 8;
  const float4* dptr = (const float4*)(s_dst + jbase + wv * 32 + quad * 8);
  const unsigned short* hbase =
      hTf + ((size_t)(jbase >> 5) + wv) * 2048 + (size_t)lane * 8;

  // depth-2 named prefetch: chunk c (suffix a) / c+1 (suffix b)
  unsigned long long MAa = mptrA[0], MBa = mptrB[0];
  unsigned long long MAb = mptrA[2], MBb = mptrB[2];
  float4 D0a = dptr[0],  D1a = dptr[1];
  float4 D0b = dptr[32], D1b = dptr[33];

  auto phase = [&](int c, unsigned long long& MA, unsigned long long& MB,
                   float4& D0, float4& D1) __attribute__((always_inline)) {
    // hv loads first: L2 latency covered by the pv compute below
    const unsigned short* hc = hbase + (size_t)c * 8192;
    const uint4 hv0 = *(const uint4*)(hc + 0 * 512);
    const uint4 hv1 = *(const uint4*)(hc + 1 * 512);
    const uint4 hv2 = *(const uint4*)(hc + 2 * 512);
    const uint4 hv3 = *(const uint4*)(hc + 3 * 512);

    const unsigned int BA = (unsigned int)(MA >> sh) & 0xffu;
    const unsigned int BB = (unsigned int)(MB >> sh) & 0xffu;
    float pvA[8], pvB[8];
    const float* dd0 = (const float*)&D0;
    const float* dd1 = (const float*)&D1;
#pragma unroll
    for (int j = 0; j < 4; ++j) {
      const float d = dd0[j];
      const float eA = lrelu(ssA + d);
      const float eB = lrelu(ssB + d);
      pvA[j] = (BA >> j) & 1u ? __expf(eA - mrA) : 0.f;
      pvB[j] = (BB >> j) & 1u ? __expf(eB - mrB) : 0.f;
    }
#pragma unroll
    for (int j = 0; j < 4; ++j) {
      const float d = dd1[j];
      const float eA = lrelu(ssA + d);
      const float eB = lrelu(ssB + d);
      pvA[4 + j] = (BA >> (4 + j)) & 1u ? __expf(eA - mrA) : 0.f;
      pvB[4 + j] = (BB >> (4 + j)) & 1u ? __expf(eB - mrB) : 0.f;
    }
    bf16x8 psA, psB;
#pragma unroll
    for (int j = 0; j < 8; ++j) {
      lA += pvA[j];  lB += pvB[j];
      psA[j] = (short)f2bf(pvA[j]);
      psB[j] = (short)f2bf(pvB[j]);
    }

    if (c + 2 < kChunks) {   // depth-2 prefetch into this phase's registers
      MA = mptrA[(c + 2) * 2]; MB = mptrB[(c + 2) * 2];
      D0 = dptr[(c + 2) * 32]; D1 = dptr[(c + 2) * 32 + 1];
    }

    aA0 = __builtin_amdgcn_mfma_f32_16x16x32_bf16(psA, __builtin_bit_cast(bf16x8, hv0), aA0, 0, 0, 0);
    aB0 = __builtin_amdgcn_mfma_f32_16x16x32_bf16(psB, __builtin_bit_cast(bf16x8, hv0), aB0, 0, 0, 0);
    aA1 = __builtin_amdgcn_mfma_f32_16x16x32_bf16(psA, __builtin_bit_cast(bf16x8, hv1), aA1, 0, 0, 0);
    aB1 = __builtin_amdgcn_mfma_f32_16x16x32_bf16(psB, __builtin_bit_cast(bf16x8, hv1), aB1, 0, 0, 0);
    aA2 = __builtin_amdgcn_mfma_f32_16x16x32_bf16(psA, __builtin_bit_cast(bf16x8, hv2), aA2, 0, 0, 0);
    aB2 = __builtin_amdgcn_mfma_f32_16x16x32_bf16(psB, __builtin_bit_cast(bf16x8, hv2), aB2, 0, 0, 0);
    aA3 = __builtin_amdgcn_mfma_f32_16x16x32_bf16(psA, __builtin_bit_cast(bf16x8, hv3), aA3, 0, 0, 0);
    aB3 = __builtin_amdgcn_mfma_f32_16x16x32_bf16(psB, __builtin_bit_cast(bf16x8, hv3), aB3, 0, 0, 0);
  };

  for (int c = 0; c < kChunks; c += 2) {
    phase(c,     MAa, MBa, D0a, D1a);
    phase(c + 1, MAb, MBb, D0b, D1b);
  }

  // ---- cross-wave reduction (only barrier) ----
  lA += __shfl_xor(lA, 16, 64);
  lA += __shfl_xor(lA, 32, 64);
  lB += __shfl_xor(lB, 16, 64);
  lB += __shfl_xor(lB, 32, 64);
  if (quad == 0) { Rl[wv][mrow] = lA; Rl[wv][16 + mrow] = lB; }

#pragma unroll
  for (int reg = 0; reg < 4; ++reg) {
    const int rA = quad * 4 + reg, rB = 16 + quad * 4 + reg;
    Racc[wv][rA][ 0 + mrow] = aA0[reg];
    Racc[wv][rA][16 + mrow] = aA1[reg];
    Racc[wv][rA][32 + mrow] = aA2[reg];
    Racc[wv][rA][48 + mrow] = aA3[reg];
    Racc[wv][rB][ 0 + mrow] = aB0[reg];
    Racc[wv][rB][16 + mrow] = aB1[reg];
    Racc[wv][rB][32 + mrow] = aB2[reg];
    Racc[wv][rB][48 + mrow] = aB3[reg];
  }
  __syncthreads();

  float* ab = accp + (size_t)b * 32 * 64;
#pragma unroll
  for (int s = 0; s < 8; ++s) {
    const int idx = s * 256 + t;
    const int r = idx >> 6, f = idx & 63;
    ab[idx] = Racc[0][r][f] + Racc[1][r][f] + Racc[2][r][f] + Racc[3][r][f];
  }
  if (t < 32) lp[(size_t)b * 32 + t] = Rl[0][t] + Rl[1][t] + Rl[2][t] + Rl[3][t];
}

// ---------------------------------------------------------------------------
// k_comb: out[i][f] = elu( (sum_q accp) / (sum_q lp) ); accp now [b][32][64]
// with b = (i>>5)*4 + quarter.
// ---------------------------------------------------------------------------
__global__ __launch_bounds__(256) void k_comb(const float* __restrict__ accp,
                                              const float* __restrict__ lp,
                                              float* __restrict__ out)
{
  const int gid = blockIdx.x * 256 + threadIdx.x;   // 0..524287
  const int i = gid >> 6, f = gid & 63;
  const int ib = i >> 5, il = i & 31;
  const int b0 = ib * kJSplit;
  float a = 0.f, l = 0.f;
#pragma unroll
  for (int qq = 0; qq < kJSplit; ++qq) {
    a += accp[((size_t)(b0 + qq) * 32 + il) * 64 + f];
    l += lp[(size_t)(b0 + qq) * 32 + il];
  }
  float v = a / l;
  v = v > 0.f ? v : __expf(v) - 1.f;
  out[gid] = v;
}

extern "C" void kernel_launch(void* const* d_in, const int* in_sizes, int n_in,
                              void* d_out, int out_size, void* d_ws, size_t ws_size,
                              hipStream_t stream) {
  const float* X   = (const float*)d_in[0];   // [8192][512]
  const int*   adj = (const int*)d_in[1];     // [8192][8192]
  const float* W   = (const float*)d_in[2];   // [512][64]
  const float* A   = (const float*)d_in[3];   // [128]
  float* out = (float*)d_out;                 // [8192][64] fp32

  char* ws = (char*)d_ws;
  unsigned long long* mask = (unsigned long long*)ws;  ws += (size_t)kN * 128 * 8;  // 8 MB
  unsigned short* hTf = (unsigned short*)ws;  ws += (size_t)kN * kFout * 2;         // 1 MB
  float* s_src = (float*)ws;                  ws += kN * 4;
  float* s_dst = (float*)ws;                  ws += kN * 4;
  unsigned int* Smax_u = (unsigned int*)ws;   ws += 256;
  float* accp  = (float*)ws;                  ws += (size_t)1024 * 32 * 64 * 4;     // 8 MB
  float* lp    = (float*)ws;                  // 128 KB

  hipMemsetAsync(Smax_u, 0, 4, stream);       // capture-safe (memset node)
  k_prep <<<2048 + 512, 256, 0, stream>>>(adj, X, W, A, mask, hTf, s_src, s_dst, Smax_u);
  k_attn <<<1024, 256, 0, stream>>>(mask, hTf, s_src, s_dst, Smax_u, accp, lp);
  k_comb <<<kN * kFout / 256, 256, 0, stream>>>(accp, lp, out);
}